// Round 7
// baseline (634.793 us; speedup 1.0000x reference)
//
#include <hip/hip_runtime.h>
#include <hip/hip_bf16.h>
#include <math.h>
#include <stdint.h>

typedef _Float16 f16;
typedef _Float16 half8 __attribute__((ext_vector_type(8)));
typedef float f32x4 __attribute__((ext_vector_type(4)));

#define B_ 16
#define S_ 4096
#define D_ 1024
#define F_ 1024
#define TOK (B_*S_)
#define TB2 256        // token tile
#define FB 128         // f tile
#define NFB (F_/FB)    // 8
#define BK3 32         // K step
#define NT3 (D_/BK3)   // 32
#define NS 16
#define CS (S_/NS)     // 256

// async global->LDS, 16B per lane; lds dest = wave-uniform base + lane*16 (HW)
__device__ __forceinline__ void gload_lds16(const void* g, void* l) {
    __builtin_amdgcn_global_load_lds(
        (__attribute__((address_space(1))) const unsigned int*)(unsigned long long)(uintptr_t)g,
        (__attribute__((address_space(3))) unsigned int*)(unsigned int)(uintptr_t)l,
        16, 0, 0);
}

__device__ __forceinline__ void fma4(float4& a, float s, const float4& wv) {
    a.x += s * wv.x; a.y += s * wv.y; a.z += s * wv.z; a.w += s * wv.w;
}
__device__ __forceinline__ void wtanh4(float4& acc, float pw, const float4& a) {
    acc.x += pw * tanhf(a.x); acc.y += pw * tanhf(a.y);
    acc.z += pw * tanhf(a.z); acc.w += pw * tanhf(a.w);
}

// ---------------- kernel 0a: convert x fp32 -> fp16 ----------------
__global__ void cvt_x(const float* __restrict__ x, f16* __restrict__ xh) {
    size_t i = ((size_t)blockIdx.x * 256 + threadIdx.x) * 8;
    float4 a = *(const float4*)(x + i);
    float4 b = *(const float4*)(x + i + 4);
    half8 h = {(f16)a.x,(f16)a.y,(f16)a.z,(f16)a.w,
               (f16)b.x,(f16)b.y,(f16)b.z,(f16)b.w};
    *(half8*)(xh + i) = h;
}

// ------------- kernel 0b: transpose+convert Wk,Wq -> wt[2][F][D] -------------
__global__ void cvt_w(const float* __restrict__ Wk, const float* __restrict__ Wq,
                      f16* __restrict__ wt) {
    __shared__ float tile[32][33];
    const float* W = (blockIdx.z == 0) ? Wk : Wq;
    f16* outp = wt + (size_t)blockIdx.z * D_ * F_;
    int x0 = blockIdx.x * 32, y0 = blockIdx.y * 32;
    int tx = threadIdx.x, ty = threadIdx.y;
#pragma unroll
    for (int i = 0; i < 4; i++)
        tile[ty + i*8][tx] = W[(size_t)(y0 + ty + i*8) * F_ + x0 + tx];
    __syncthreads();
#pragma unroll
    for (int i = 0; i < 4; i++)
        outp[(size_t)(x0 + ty + i*8) * D_ + y0 + tx] = (f16)tile[tx][ty + i*8];
}

// ------------- kernel 1: fused Q/K GEMM + tanh + diag-dot partials -------------
// 256x128 tile, 8 waves, BK=32, 4 LDS slots, prefetch-3, counted vmcnt(8).
// m201-style per-phase barrier pairs: each K-tile = 2 phases of
// {ds_read ∥ stage-issue → bar → lgkmcnt(0) → setprio(1) 16xMFMA setprio(0) → bar}.
// Quad-XOR LDS swizzle both-sides (T2). XCD-chunked block swizzle (T1).
__launch_bounds__(512, 2)
__global__ void score_gemm(const f16* __restrict__ xh, const f16* __restrict__ wt,
                           float* __restrict__ part) {
    __shared__ __align__(16) f16 Xs[4][TB2 * BK3];   // 4 x 16 KB
    __shared__ __align__(16) f16 Ks[4][FB * BK3];    // 4 x 8 KB
    __shared__ __align__(16) f16 Qs[4][FB * BK3];    // 4 x 8 KB
    __shared__ float sred[2][TB2];

    // T1: bijective XCD chunk swizzle (2048 blocks, 8 XCDs -> 256 each)
    const int hid  = blockIdx.x + blockIdx.y * NFB;
    const int orig = (hid & 7) * 256 + (hid >> 3);
    const int fb   = orig & 7;
    const int f0   = fb * FB;
    const int tok0 = (orig >> 3) * TB2;

    const int t    = threadIdx.x;     // 0..511
    const int lane = t & 63;
    const int w    = t >> 6;          // 0..7
    const int wr   = (w >> 1) * 64;   // token offset of wave sub-tile
    const int wc   = (w & 1) * 64;    // f offset of wave sub-tile

    const f16* wK = wt + (size_t)f0 * D_;
    const f16* wQ = wt + (size_t)D_ * F_ + (size_t)f0 * D_;

    // staging constants; source quad pre-swizzled: qsrc = q ^ ((row>>1)&3)
    const int cX0 = t, cX1 = t + 512;
    const int rX0 = cX0 >> 2, rX1 = cX1 >> 2;
    const int qX0 = (cX0 & 3) ^ ((rX0 >> 1) & 3);
    const int qX1 = (cX1 & 3) ^ ((rX1 >> 1) & 3);
    const f16* srcX0 = xh + (size_t)(tok0 + rX0) * D_ + qX0 * 8;
    const f16* srcX1 = xh + (size_t)(tok0 + rX1) * D_ + qX1 * 8;
    const int rW = t >> 2;
    const int qW = (t & 3) ^ ((rW >> 1) & 3);
    const f16* srcK = wK + (size_t)rW * D_ + qW * 8;
    const f16* srcQ = wQ + (size_t)rW * D_ + qW * 8;
    const int wbase = w * 1024;       // wave-uniform LDS byte base for staging

    // fragment read offsets (f16 elems; swizzled read side of the involution)
    int offA[4], offB[4];
#pragma unroll
    for (int m = 0; m < 4; ++m) {
        int row = wr + m * 16 + (lane & 15);
        int q   = (lane >> 4) ^ ((row >> 1) & 3);
        offA[m] = row * 32 + q * 8;
    }
#pragma unroll
    for (int n = 0; n < 4; ++n) {
        int row = wc + n * 16 + (lane & 15);
        int q   = (lane >> 4) ^ ((row >> 1) & 3);
        offB[n] = row * 32 + q * 8;
    }

#define STAGE_X(slot, kof) do {                                   \
        char* xb = (char*)Xs[slot] + wbase;                       \
        gload_lds16(srcX0 + (kof), xb);                           \
        gload_lds16(srcX1 + (kof), xb + 8192);                    \
    } while (0)
#define STAGE_W(slot, kof) do {                                   \
        gload_lds16(srcK + (kof), (char*)Ks[slot] + wbase);       \
        gload_lds16(srcQ + (kof), (char*)Qs[slot] + wbase);       \
    } while (0)

    f32x4 accQ[4][4] = {};
    f32x4 accK[4][4] = {};

    // prologue: stage tiles 0,1,2 (12 loads/wave), drain tile-0's 4
    STAGE_X(0, 0);  STAGE_W(0, 0);
    STAGE_X(1, 32); STAGE_W(1, 32);
    STAGE_X(2, 64); STAGE_W(2, 64);
    asm volatile("s_waitcnt vmcnt(8)" ::: "memory");
    __builtin_amdgcn_s_barrier();
    __builtin_amdgcn_sched_barrier(0);

    for (int kt = 0; kt < NT3; ++kt) {
        const int slot  = kt & 3;
        const int pslot = (kt + 3) & 3;
        const int kof   = (kt + 3) * BK3;
        const f16* Xb = Xs[slot];
        const f16* Kb = Ks[slot];
        const f16* Qb = Qs[slot];

        // ---- Phase 1: ds_read A + B_K ∥ X-prefetch → bar → 16 MFMA accK
        half8 aF[4], bKf[4];
#pragma unroll
        for (int m = 0; m < 4; ++m) aF[m]  = *(const half8*)(Xb + offA[m]);
#pragma unroll
        for (int n = 0; n < 4; ++n) bKf[n] = *(const half8*)(Kb + offB[n]);
        if (kt < NT3 - 3) STAGE_X(pslot, kof);
        __builtin_amdgcn_s_barrier();
        asm volatile("s_waitcnt lgkmcnt(0)" ::: "memory");
        __builtin_amdgcn_sched_barrier(0);
        __builtin_amdgcn_s_setprio(1);
#pragma unroll
        for (int n = 0; n < 4; ++n)
#pragma unroll
            for (int m = 0; m < 4; ++m)
                accK[m][n] = __builtin_amdgcn_mfma_f32_16x16x32_f16(aF[m], bKf[n], accK[m][n], 0, 0, 0);
        __builtin_amdgcn_s_setprio(0);
        __builtin_amdgcn_s_barrier();

        // ---- Phase 2: ds_read B_Q ∥ K/Q-prefetch → counted vmcnt → bar → 16 MFMA accQ
        half8 bQf[4];
#pragma unroll
        for (int n = 0; n < 4; ++n) bQf[n] = *(const half8*)(Qb + offB[n]);
        if (kt < NT3 - 3) STAGE_W(pslot, kof);
        if (kt < NT3 - 3) {
            asm volatile("s_waitcnt vmcnt(8)" ::: "memory");
        } else if (kt == NT3 - 3) {
            asm volatile("s_waitcnt vmcnt(4)" ::: "memory");
        } else if (kt == NT3 - 2) {
            asm volatile("s_waitcnt vmcnt(0)" ::: "memory");
        }
        __builtin_amdgcn_s_barrier();
        asm volatile("s_waitcnt lgkmcnt(0)" ::: "memory");
        __builtin_amdgcn_sched_barrier(0);
        __builtin_amdgcn_s_setprio(1);
#pragma unroll
        for (int n = 0; n < 4; ++n)
#pragma unroll
            for (int m = 0; m < 4; ++m)
                accQ[m][n] = __builtin_amdgcn_mfma_f32_16x16x32_f16(aF[m], bQf[n], accQ[m][n], 0, 0, 0);
        __builtin_amdgcn_s_setprio(0);
        if (kt < NT3 - 1) __builtin_amdgcn_s_barrier();
    }
#undef STAGE_X
#undef STAGE_W

    // epilogue: tanh, product, reduce over f within wave, combine 2 f-wave-cols
#pragma unroll
    for (int m = 0; m < 4; ++m) {
        float s[4] = {0.f, 0.f, 0.f, 0.f};
#pragma unroll
        for (int n = 0; n < 4; ++n)
#pragma unroll
            for (int j = 0; j < 4; ++j)
                s[j] += tanhf(accQ[m][n][j]) * tanhf(accK[m][n][j]);
#pragma unroll
        for (int j = 0; j < 4; ++j) {
            s[j] += __shfl_xor(s[j], 1);
            s[j] += __shfl_xor(s[j], 2);
            s[j] += __shfl_xor(s[j], 4);
            s[j] += __shfl_xor(s[j], 8);
        }
        if ((lane & 15) == 0) {
            int g = lane >> 4;
#pragma unroll
            for (int j = 0; j < 4; ++j)
                sred[w & 1][wr + m * 16 + g * 4 + j] = s[j];
        }
    }
    __syncthreads();
    if (t < TB2)
        part[(size_t)fb * TOK + tok0 + t] = sred[0][t] + sred[1][t];
}

// ------------- kernel 2: per-batch softmax over S -------------
__global__ void softmax_k(const float* __restrict__ part, float* __restrict__ out) {
    __shared__ float sc[S_];
    __shared__ float red[256];
    const int b = blockIdx.x, t = threadIdx.x;
    float lmax = -1e30f;
    for (int i = t; i < S_; i += 256) {
        float s = 0.f;
#pragma unroll
        for (int fb = 0; fb < NFB; ++fb) s += part[(size_t)fb * TOK + b * S_ + i];
        sc[i] = s;
        lmax = fmaxf(lmax, s);
    }
    red[t] = lmax; __syncthreads();
    for (int o = 128; o > 0; o >>= 1) { if (t < o) red[t] = fmaxf(red[t], red[t + o]); __syncthreads(); }
    const float mx = red[0]; __syncthreads();
    float lsum = 0.f;
    for (int i = t; i < S_; i += 256) { float e = expf(sc[i] - mx); sc[i] = e; lsum += e; }
    red[t] = lsum; __syncthreads();
    for (int o = 128; o > 0; o >>= 1) { if (t < o) red[t] += red[t + o]; __syncthreads(); }
    const float inv = 1.0f / red[0];
    for (int i = t; i < S_; i += 256)
        out[(size_t)B_ * F_ + (size_t)b * S_ + i] = sc[i] * inv;
}

// ------------- kernel 3: sparse value pass, one block per (b,chunk), all f -------------
__launch_bounds__(256)
__global__ void value_k3(const float* __restrict__ x, const float* __restrict__ Wv,
                         const float* __restrict__ p_in, float* __restrict__ vpart) {
    __shared__ __align__(16) float xs[4][D_];   // 16 KB
    __shared__ float ps[CS];
    __shared__ int   idxs[CS];
    __shared__ int   wsum[4];
    const int b = blockIdx.x, c = blockIdx.y;
    const int t = threadIdx.x, lane = t & 63, w = t >> 6;
    const int s0 = c * CS;

    float p = p_in[(size_t)b * S_ + s0 + t];
    bool flag = p > 1e-7f;
    unsigned long long mask = __ballot(flag);
    if (lane == 0) wsum[w] = __popcll(mask);
    __syncthreads();
    int base = 0;
#pragma unroll
    for (int i = 0; i < 4; ++i) if (i < w) base += wsum[i];
    const int cnt = wsum[0] + wsum[1] + wsum[2] + wsum[3];
    if (flag) {
        int pos = base + __popcll(mask & ((1ull << lane) - 1ull));
        idxs[pos] = s0 + t;
        ps[pos] = p;
    }
    __syncthreads();

    float4 acc = {0.f, 0.f, 0.f, 0.f};
    for (int g = 0; g < cnt; g += 4) {
        __syncthreads();
#pragma unroll
        for (int r = 0; r < 4; ++r) {
            float4 v = {0.f, 0.f, 0.f, 0.f};
            if (g + r < cnt)
                v = ((const float4*)(x + ((size_t)b * S_ + idxs[g + r]) * D_))[t];
            ((float4*)xs[r])[t] = v;
        }
        __syncthreads();
        float4 a0 = {0,0,0,0}, a1 = {0,0,0,0}, a2 = {0,0,0,0}, a3 = {0,0,0,0};
#pragma unroll 2
        for (int dq = 0; dq < D_ / 4; ++dq) {
            const float* wr = Wv + (size_t)dq * 4 * F_;
            float4 wv0 = ((const float4*)(wr        ))[t];
            float4 wv1 = ((const float4*)(wr + F_   ))[t];
            float4 wv2 = ((const float4*)(wr + 2*F_ ))[t];
            float4 wv3 = ((const float4*)(wr + 3*F_ ))[t];
            float4 x0 = ((const float4*)xs[0])[dq];
            float4 x1 = ((const float4*)xs[1])[dq];
            float4 x2 = ((const float4*)xs[2])[dq];
            float4 x3 = ((const float4*)xs[3])[dq];
            fma4(a0, x0.x, wv0); fma4(a0, x0.y, wv1); fma4(a0, x0.z, wv2); fma4(a0, x0.w, wv3);
            fma4(a1, x1.x, wv0); fma4(a1, x1.y, wv1); fma4(a1, x1.z, wv2); fma4(a1, x1.w, wv3);
            fma4(a2, x2.x, wv0); fma4(a2, x2.y, wv1); fma4(a2, x2.z, wv2); fma4(a2, x2.w, wv3);
            fma4(a3, x3.x, wv0); fma4(a3, x3.y, wv1); fma4(a3, x3.z, wv2); fma4(a3, x3.w, wv3);
        }
        int rem = cnt - g;
        if (rem > 0) wtanh4(acc, ps[g + 0], a0);
        if (rem > 1) wtanh4(acc, ps[g + 1], a1);
        if (rem > 2) wtanh4(acc, ps[g + 2], a2);
        if (rem > 3) wtanh4(acc, ps[g + 3], a3);
    }
    ((float4*)(vpart + ((size_t)c * B_ + b) * F_))[t] = acc;
}

// ------------- kernel 4: reduce chunk partials -------------
__global__ void value_red(const float* __restrict__ vpart, float* __restrict__ out) {
    int i = blockIdx.x * 256 + threadIdx.x;
    float s = 0.f;
#pragma unroll
    for (int c = 0; c < NS; ++c) s += vpart[(size_t)c * B_ * F_ + i];
    out[i] = s;
}

extern "C" void kernel_launch(void* const* d_in, const int* in_sizes, int n_in,
                              void* d_out, int out_size, void* d_ws, size_t ws_size,
                              hipStream_t stream) {
    const float* x  = (const float*)d_in[0];
    const float* Wk = (const float*)d_in[1];
    const float* Wq = (const float*)d_in[2];
    const float* Wv = (const float*)d_in[3];
    float* out = (float*)d_out;
    char* ws = (char*)d_ws;

    f16*   xh   = (f16*)ws;                                              // 128 MB
    f16*   wt   = (f16*)(ws + (size_t)TOK * D_ * 2);                     // 4 MB
    float* part = (float*)(ws + (size_t)TOK * D_ * 2 + 2 * (size_t)D_ * F_ * 2); // 2 MB

    cvt_x<<<TOK * D_ / 8 / 256, 256, 0, stream>>>(x, xh);
    cvt_w<<<dim3(32, 32, 2), dim3(32, 8), 0, stream>>>(Wk, Wq, wt);
    score_gemm<<<dim3(NFB, TOK / TB2), 512, 0, stream>>>(xh, wt, part);
    softmax_k<<<B_, 256, 0, stream>>>(part, out);
    float* vpart = part;
    const float* p_in = out + (size_t)B_ * F_;
    value_k3<<<dim3(B_, NS), 256, 0, stream>>>(x, Wv, p_in, vpart);
    value_red<<<B_ * F_ / 256, 256, 0, stream>>>(vpart, out);
}

// Round 8
// 600.147 us; speedup vs baseline: 1.0577x; 1.0577x over previous
//
#include <hip/hip_runtime.h>
#include <hip/hip_bf16.h>
#include <math.h>
#include <stdint.h>

typedef _Float16 f16;
typedef _Float16 half8 __attribute__((ext_vector_type(8)));
typedef float f32x4 __attribute__((ext_vector_type(4)));

#define B_ 16
#define S_ 4096
#define D_ 1024
#define F_ 1024
#define TOK (B_*S_)
#define TB3 128        // token tile
#define FB3 64         // f tile
#define NFB3 16        // F_/FB3
#define NT3 32         // D_/32 K-tiles
#define NSV 4          // value-pass S chunks
#define CSV (S_/NSV)   // 1024

// async global->LDS, 16B per lane; lds dest = wave-uniform base + lane*16 (HW)
__device__ __forceinline__ void gload_lds16(const void* g, void* l) {
    __builtin_amdgcn_global_load_lds(
        (__attribute__((address_space(1))) const unsigned int*)(unsigned long long)(uintptr_t)g,
        (__attribute__((address_space(3))) unsigned int*)(unsigned int)(uintptr_t)l,
        16, 0, 0);
}

__device__ __forceinline__ void fma4(float4& a, float s, const float4& wv) {
    a.x += s * wv.x; a.y += s * wv.y; a.z += s * wv.z; a.w += s * wv.w;
}
__device__ __forceinline__ void wtanh4(float4& acc, float pw, const float4& a) {
    acc.x += pw * tanhf(a.x); acc.y += pw * tanhf(a.y);
    acc.z += pw * tanhf(a.z); acc.w += pw * tanhf(a.w);
}

// ---------------- kernel 0a: convert x fp32 -> fp16 ----------------
__global__ void cvt_x(const float* __restrict__ x, f16* __restrict__ xh) {
    size_t i = ((size_t)blockIdx.x * 256 + threadIdx.x) * 8;
    float4 a = *(const float4*)(x + i);
    float4 b = *(const float4*)(x + i + 4);
    half8 h = {(f16)a.x,(f16)a.y,(f16)a.z,(f16)a.w,
               (f16)b.x,(f16)b.y,(f16)b.z,(f16)b.w};
    *(half8*)(xh + i) = h;
}

// ------------- kernel 0b: transpose+convert Wk,Wq -> wt[2][F][D] -------------
__global__ void cvt_w(const float* __restrict__ Wk, const float* __restrict__ Wq,
                      f16* __restrict__ wt) {
    __shared__ float tile[32][33];
    const float* W = (blockIdx.z == 0) ? Wk : Wq;
    f16* outp = wt + (size_t)blockIdx.z * D_ * F_;
    int x0 = blockIdx.x * 32, y0 = blockIdx.y * 32;
    int tx = threadIdx.x, ty = threadIdx.y;
#pragma unroll
    for (int i = 0; i < 4; i++)
        tile[ty + i*8][tx] = W[(size_t)(y0 + ty + i*8) * F_ + x0 + tx];
    __syncthreads();
#pragma unroll
    for (int i = 0; i < 4; i++)
        outp[(size_t)(x0 + ty + i*8) * D_ + y0 + tx] = (f16)tile[tx][ty + i*8];
}

// ------------- kernel 1: fused Q/K GEMM + tanh + diag-dot partials -------------
// 128x64 tile, 4 waves (2 tok-groups x 2 f-groups), each wave 64 tok x 32 f for
// BOTH matrices (acc = 64 regs -> ~140 total -> 3 waves/SIMD, 3 blocks/CU).
// BK=32, 3 LDS slots (49KB), prefetch-2, counted vmcnt(4), ONE barrier/tile.
// T2 quad-XOR swizzle both-sides; T1 XCD chunk swizzle.
__launch_bounds__(256, 3)
__global__ void score_gemm(const f16* __restrict__ xh, const f16* __restrict__ wt,
                           float* __restrict__ part) {
    __shared__ __align__(16) f16 Xs[3][TB3 * 32];   // 3 x 8 KB
    __shared__ __align__(16) f16 Ks[3][FB3 * 32];   // 3 x 4 KB
    __shared__ __align__(16) f16 Qs[3][FB3 * 32];   // 3 x 4 KB
    __shared__ float sred[2][TB3];                  // 1 KB

    // T1: 8192 blocks, 8 XCDs -> 1024 contiguous origs each; fb fastest within
    const int hid  = blockIdx.x + blockIdx.y * NFB3;
    const int orig = (hid & 7) * 1024 + (hid >> 3);
    const int fb   = orig & 15;
    const int f0   = fb * FB3;
    const int tok0 = (orig >> 4) * TB3;

    const int t = threadIdx.x, lane = t & 63, w = t >> 6;
    const int wr = (w >> 1) * 64;     // token offset of wave sub-tile
    const int wc = (w & 1) * 32;      // f offset of wave sub-tile

    const f16* wK = wt + (size_t)f0 * D_;
    const f16* wQ = wt + (size_t)D_ * F_ + (size_t)f0 * D_;

    // staging sources, pre-swizzled quad (involution q ^ ((row>>1)&3))
    const int rx0 = t >> 2,         qx0 = (t & 3) ^ ((rx0 >> 1) & 3);
    const int rx1 = (t + 256) >> 2, qx1 = (t & 3) ^ ((rx1 >> 1) & 3);
    const f16* srcX0 = xh + (size_t)(tok0 + rx0) * D_ + qx0 * 8;
    const f16* srcX1 = xh + (size_t)(tok0 + rx1) * D_ + qx1 * 8;
    const int rw = t >> 2,          qw = (t & 3) ^ ((rw >> 1) & 3);
    const f16* srcK = wK + (size_t)rw * D_ + qw * 8;
    const f16* srcQ = wQ + (size_t)rw * D_ + qw * 8;
    const int wbase = w * 1024;       // wave-uniform LDS byte base

    // fragment read offsets (swizzled read side)
    int offA[4], offB[2];
#pragma unroll
    for (int m = 0; m < 4; ++m) {
        int row = wr + m * 16 + (lane & 15);
        int q   = (lane >> 4) ^ ((row >> 1) & 3);
        offA[m] = row * 32 + q * 8;
    }
#pragma unroll
    for (int n = 0; n < 2; ++n) {
        int row = wc + n * 16 + (lane & 15);
        int q   = (lane >> 4) ^ ((row >> 1) & 3);
        offB[n] = row * 32 + q * 8;
    }

#define STAGE(sl, kof) do {                                           \
        gload_lds16(srcX0 + (kof), (char*)Xs[sl] + wbase);            \
        gload_lds16(srcX1 + (kof), (char*)Xs[sl] + 4096 + wbase);     \
        gload_lds16(srcK  + (kof), (char*)Ks[sl] + wbase);            \
        gload_lds16(srcQ  + (kof), (char*)Qs[sl] + wbase);            \
    } while (0)

    f32x4 accK[4][2] = {};
    f32x4 accQ[4][2] = {};

    // prologue: stage tiles 0,1 (8 loads); wait tile-0's 4
    STAGE(0, 0);
    STAGE(1, 32);
    asm volatile("s_waitcnt vmcnt(4)" ::: "memory");
    __builtin_amdgcn_s_barrier();

#pragma unroll 1
    for (int kt = 0; kt < NT3; ++kt) {
        const int cur = kt % 3;
        if (kt < NT3 - 2) {
            const int nxt = (kt + 2) % 3;
            STAGE(nxt, (kt + 2) * 32);
        }
        const f16* Xb = Xs[cur];
        const f16* Kb = Ks[cur];
        const f16* Qb = Qs[cur];

        half8 aF[4], bKf[2], bQf[2];
#pragma unroll
        for (int m = 0; m < 4; ++m) aF[m]  = *(const half8*)(Xb + offA[m]);
#pragma unroll
        for (int n = 0; n < 2; ++n) {
            bKf[n] = *(const half8*)(Kb + offB[n]);
            bQf[n] = *(const half8*)(Qb + offB[n]);
        }
#pragma unroll
        for (int n = 0; n < 2; ++n)
#pragma unroll
            for (int m = 0; m < 4; ++m) {
                accK[m][n] = __builtin_amdgcn_mfma_f32_16x16x32_f16(aF[m], bKf[n], accK[m][n], 0, 0, 0);
                accQ[m][n] = __builtin_amdgcn_mfma_f32_16x16x32_f16(aF[m], bQf[n], accQ[m][n], 0, 0, 0);
            }

        if (kt < NT3 - 2) {
            asm volatile("s_waitcnt vmcnt(4)" ::: "memory");   // next tile ready, 4 stay in flight
        } else if (kt == NT3 - 2) {
            asm volatile("s_waitcnt vmcnt(0)" ::: "memory");   // last tile
        }
        if (kt < NT3 - 1) __builtin_amdgcn_s_barrier();
    }
#undef STAGE

    // epilogue: tanh, product, reduce over f, combine 2 f-wave-cols
#pragma unroll
    for (int m = 0; m < 4; ++m) {
        float s[4] = {0.f, 0.f, 0.f, 0.f};
#pragma unroll
        for (int n = 0; n < 2; ++n)
#pragma unroll
            for (int j = 0; j < 4; ++j)
                s[j] += tanhf(accQ[m][n][j]) * tanhf(accK[m][n][j]);
#pragma unroll
        for (int j = 0; j < 4; ++j) {
            s[j] += __shfl_xor(s[j], 1);
            s[j] += __shfl_xor(s[j], 2);
            s[j] += __shfl_xor(s[j], 4);
            s[j] += __shfl_xor(s[j], 8);
        }
        if ((lane & 15) == 0) {
            int g = lane >> 4;
#pragma unroll
            for (int j = 0; j < 4; ++j)
                sred[w & 1][wr + m * 16 + g * 4 + j] = s[j];
        }
    }
    __syncthreads();
    if (t < TB3)
        part[(size_t)fb * TOK + tok0 + t] = sred[0][t] + sred[1][t];
}

// ------------- kernel 2: per-batch softmax over S -------------
__global__ void softmax_k(const float* __restrict__ part, float* __restrict__ out) {
    __shared__ float sc[S_];
    __shared__ float red[256];
    const int b = blockIdx.x, t = threadIdx.x;
    float lmax = -1e30f;
    for (int i = t; i < S_; i += 256) {
        float s = 0.f;
#pragma unroll
        for (int fb = 0; fb < NFB3; ++fb) s += part[(size_t)fb * TOK + b * S_ + i];
        sc[i] = s;
        lmax = fmaxf(lmax, s);
    }
    red[t] = lmax; __syncthreads();
    for (int o = 128; o > 0; o >>= 1) { if (t < o) red[t] = fmaxf(red[t], red[t + o]); __syncthreads(); }
    const float mx = red[0]; __syncthreads();
    float lsum = 0.f;
    for (int i = t; i < S_; i += 256) { float e = expf(sc[i] - mx); sc[i] = e; lsum += e; }
    red[t] = lsum; __syncthreads();
    for (int o = 128; o > 0; o >>= 1) { if (t < o) red[t] += red[t + o]; __syncthreads(); }
    const float inv = 1.0f / red[0];
    for (int i = t; i < S_; i += 256)
        out[(size_t)B_ * F_ + (size_t)b * S_ + i] = sc[i] * inv;
}

// ------------- kernel 3: sparse value pass, NSV chunks, groups of 8 -------------
__launch_bounds__(256)
__global__ void value_k4(const float* __restrict__ x, const float* __restrict__ Wv,
                         const float* __restrict__ p_in, float* __restrict__ vpart) {
    __shared__ __align__(16) float xs[8][D_];   // 32 KB
    __shared__ float ps[CSV];
    __shared__ int   idxs[CSV];
    __shared__ int   wsum[4];
    __shared__ int   rbase_s;
    const int b = blockIdx.x, c = blockIdx.y;
    const int t = threadIdx.x, lane = t & 63, w = t >> 6;
    const int s0 = c * CSV;

    if (t == 0) rbase_s = 0;
    __syncthreads();
    // deterministic parallel compaction, 4 rounds of 256
#pragma unroll 1
    for (int r = 0; r < 4; ++r) {
        int i = r * 256 + t;
        float p = p_in[(size_t)b * S_ + s0 + i];
        bool flag = p > 1e-7f;
        unsigned long long mask = __ballot(flag);
        if (lane == 0) wsum[w] = __popcll(mask);
        __syncthreads();
        int base = rbase_s;
#pragma unroll
        for (int k = 0; k < 4; ++k) if (k < w) base += wsum[k];
        if (flag) {
            int pos = base + __popcll(mask & ((1ull << lane) - 1ull));
            idxs[pos] = s0 + i;
            ps[pos] = p;
        }
        __syncthreads();
        if (t == 0) rbase_s += wsum[0] + wsum[1] + wsum[2] + wsum[3];
        __syncthreads();
    }
    const int cnt = rbase_s;

    float4 acc = {0.f, 0.f, 0.f, 0.f};
    for (int g = 0; g < cnt; g += 8) {
        __syncthreads();
#pragma unroll
        for (int r = 0; r < 8; ++r) {
            float4 v = {0.f, 0.f, 0.f, 0.f};
            if (g + r < cnt)
                v = ((const float4*)(x + ((size_t)b * S_ + idxs[g + r]) * D_))[t];
            ((float4*)xs[r])[t] = v;          // full 4KB row per r (zero-padded)
        }
        __syncthreads();
        float4 a[8] = {};
#pragma unroll 2
        for (int dq = 0; dq < D_ / 4; ++dq) {
            const float* wrp = Wv + (size_t)dq * 4 * F_;
            float4 wv0 = ((const float4*)(wrp        ))[t];
            float4 wv1 = ((const float4*)(wrp + F_   ))[t];
            float4 wv2 = ((const float4*)(wrp + 2*F_ ))[t];
            float4 wv3 = ((const float4*)(wrp + 3*F_ ))[t];
#pragma unroll
            for (int r = 0; r < 8; ++r) {
                float4 xr = ((const float4*)xs[r])[dq];   // broadcast, conflict-free
                fma4(a[r], xr.x, wv0); fma4(a[r], xr.y, wv1);
                fma4(a[r], xr.z, wv2); fma4(a[r], xr.w, wv3);
            }
        }
#pragma unroll
        for (int r = 0; r < 8; ++r)
            if (g + r < cnt) wtanh4(acc, ps[g + r], a[r]);
    }
    ((float4*)(vpart + ((size_t)c * B_ + b) * F_))[t] = acc;
}

// ------------- kernel 4: reduce chunk partials -------------
__global__ void value_red(const float* __restrict__ vpart, float* __restrict__ out) {
    int i = blockIdx.x * 256 + threadIdx.x;
    float s = 0.f;
#pragma unroll
    for (int c = 0; c < NSV; ++c) s += vpart[(size_t)c * B_ * F_ + i];
    out[i] = s;
}

extern "C" void kernel_launch(void* const* d_in, const int* in_sizes, int n_in,
                              void* d_out, int out_size, void* d_ws, size_t ws_size,
                              hipStream_t stream) {
    const float* x  = (const float*)d_in[0];
    const float* Wk = (const float*)d_in[1];
    const float* Wq = (const float*)d_in[2];
    const float* Wv = (const float*)d_in[3];
    float* out = (float*)d_out;
    char* ws = (char*)d_ws;

    f16*   xh   = (f16*)ws;                                              // 128 MB
    f16*   wt   = (f16*)(ws + (size_t)TOK * D_ * 2);                     // 4 MB
    float* part = (float*)(ws + (size_t)TOK * D_ * 2 + 2 * (size_t)D_ * F_ * 2); // 4 MB (16 fb rows)

    cvt_x<<<TOK * D_ / 8 / 256, 256, 0, stream>>>(x, xh);
    cvt_w<<<dim3(32, 32, 2), dim3(32, 8), 0, stream>>>(Wk, Wq, wt);
    score_gemm<<<dim3(NFB3, TOK / TB3), 256, 0, stream>>>(xh, wt, part);
    softmax_k<<<B_, 256, 0, stream>>>(part, out);
    float* vpart = part;                       // reuse after softmax (256 KB)
    const float* p_in = out + (size_t)B_ * F_;
    value_k4<<<dim3(B_, NSV), 256, 0, stream>>>(x, Wv, p_in, vpart);
    value_red<<<B_ * F_ / 256, 256, 0, stream>>>(vpart, out);
}

// Round 9
// 590.130 us; speedup vs baseline: 1.0757x; 1.0170x over previous
//
#include <hip/hip_runtime.h>
#include <hip/hip_bf16.h>
#include <math.h>
#include <stdint.h>

typedef _Float16 f16;
typedef _Float16 half8 __attribute__((ext_vector_type(8)));
typedef float f32x4 __attribute__((ext_vector_type(4)));

#define B_ 16
#define S_ 4096
#define D_ 1024
#define F_ 1024
#define TOK (B_*S_)
#define TB3 128        // token tile
#define FB3 64         // f tile
#define NFB3 16        // F_/FB3
#define NT3 32         // D_/32 K-tiles
#define NSV 4          // value-pass S chunks
#define CSV (S_/NSV)   // 1024

// async global->LDS, 16B per lane; lds dest = wave-uniform base + lane*16 (HW)
__device__ __forceinline__ void gload_lds16(const void* g, void* l) {
    __builtin_amdgcn_global_load_lds(
        (__attribute__((address_space(1))) const unsigned int*)(unsigned long long)(uintptr_t)g,
        (__attribute__((address_space(3))) unsigned int*)(unsigned int)(uintptr_t)l,
        16, 0, 0);
}

__device__ __forceinline__ void fma4(float4& a, float s, const float4& wv) {
    a.x += s * wv.x; a.y += s * wv.y; a.z += s * wv.z; a.w += s * wv.w;
}
__device__ __forceinline__ void wtanh4(float4& acc, float pw, const float4& a) {
    acc.x += pw * tanhf(a.x); acc.y += pw * tanhf(a.y);
    acc.z += pw * tanhf(a.z); acc.w += pw * tanhf(a.w);
}

// ---------------- kernel 0a: convert x fp32 -> fp16 ----------------
__global__ void cvt_x(const float* __restrict__ x, f16* __restrict__ xh) {
    size_t i = ((size_t)blockIdx.x * 256 + threadIdx.x) * 8;
    float4 a = *(const float4*)(x + i);
    float4 b = *(const float4*)(x + i + 4);
    half8 h = {(f16)a.x,(f16)a.y,(f16)a.z,(f16)a.w,
               (f16)b.x,(f16)b.y,(f16)b.z,(f16)b.w};
    *(half8*)(xh + i) = h;
}

// ------- kernel 0b: pack Wk,Wq (fp32 [D][F]) -> MFMA-fragment-major f16 -------
// wtf frag index gw = ((mat*16+fb)*32 + kt)*4 + nblk ; per frag 64 lanes x 8 f16.
// lane l holds f = fb*64+nblk*16+(l&15), k = kt*32+(l>>4)*8 .. +8  (B-operand of
// mfma_f32_16x16x32_f16), stored contiguous so a wave loads it as one dwordx4.
__global__ void cvt_w2(const float* __restrict__ Wk, const float* __restrict__ Wq,
                       f16* __restrict__ wtf) {
    const int gw   = blockIdx.x * 4 + (threadIdx.x >> 6);   // 0..4095
    const int lane = threadIdx.x & 63;
    const int nblk = gw & 3, kt = (gw >> 2) & 31, fb = (gw >> 7) & 15, mat = gw >> 11;
    const float* W = mat ? Wq : Wk;
    const int f  = fb * 64 + nblk * 16 + (lane & 15);
    const int d0 = kt * 32 + (lane >> 4) * 8;
    half8 h;
#pragma unroll
    for (int e = 0; e < 8; ++e) h[e] = (f16)W[(size_t)(d0 + e) * F_ + f];
    *(half8*)(wtf + (size_t)gw * 512 + lane * 8) = h;
}

// ------------- kernel 1: fused Q/K GEMM + tanh + diag-dot partials -------------
// 128x64 tile, 4 waves, each 64 tok x 32 f for BOTH matrices.
// X: LDS-staged (4 slots x 8KB, gload_lds, T2 swizzle both-sides, prefetch-3).
// W: NO LDS — fragment-major global loads (L2-hot), register ping-pong.
// Full K-loop unroll; raw s_barrier per tile; compiler-counted vmcnt via W reg
// deps (W(kt-1) auto-wait provably forces X(kt) before its ds_read).
// T1: tok-fastest within XCD chunk (W slice stays hot in each XCD L2).
__launch_bounds__(256, 3)
__global__ void score_gemm(const f16* __restrict__ xh, const f16* __restrict__ wtf,
                           float* __restrict__ part) {
    __shared__ __align__(16) f16 Xs[4][TB3 * 32];   // 4 x 8 KB
    __shared__ float sred[2][TB3];                  // 1 KB

    // T1: 8192 blocks -> XCD chunks of 1024; within chunk fb slow, tok fast
    const int hid  = blockIdx.x;
    const int orig = (hid & 7) * 1024 + (hid >> 3);
    const int fb   = orig >> 9;                 // 0..15
    const int tok0 = (orig & 511) * TB3;

    const int t = threadIdx.x, lane = t & 63, w = t >> 6;
    const int wr = (w >> 1) * 64;     // token offset of wave sub-tile
    const int wc = (w & 1) * 32;      // f offset of wave sub-tile

    // X staging sources, pre-swizzled quad (involution q ^ ((row>>1)&3))
    const int rx0 = t >> 2,         qx0 = (t & 3) ^ ((rx0 >> 1) & 3);
    const int rx1 = (t + 256) >> 2, qx1 = (t & 3) ^ ((rx1 >> 1) & 3);
    const f16* srcX0 = xh + (size_t)(tok0 + rx0) * D_ + qx0 * 8;
    const f16* srcX1 = xh + (size_t)(tok0 + rx1) * D_ + qx1 * 8;
    const int wbase = w * 1024;       // wave-uniform LDS byte base

    // A-fragment read offsets (swizzled read side)
    int offA[4];
#pragma unroll
    for (int m = 0; m < 4; ++m) {
        int row = wr + m * 16 + (lane & 15);
        int q   = (lane >> 4) ^ ((row >> 1) & 3);
        offA[m] = row * 32 + q * 8;
    }

    // W fragment base pointers (per-lane): frag elem off = ((fb*32+kt)*4+nblk)*512
    const f16* bK = wtf + (((size_t)fb * NT3 * 4) + 2 * (w & 1)) * 512 + lane * 8;
    const f16* bQ = bK + (size_t)NFB3 * NT3 * 4 * 512;   // mat=1 half

#define STAGE_X(sl, kof) do {                                         \
        gload_lds16(srcX0 + (kof), (char*)Xs[sl] + wbase);            \
        gload_lds16(srcX1 + (kof), (char*)Xs[sl] + 4096 + wbase);     \
    } while (0)

    f32x4 accK[4][2] = {};
    f32x4 accQ[4][2] = {};
    half8 wKf[2][2], wQf[2][2];

    // prologue: X0,X1,X2 staged, then W(0) frags; vmcnt(8) forces X0;
    // MFMA(0)'s auto-wait on W(0) (newest) drains X1,X2 for iters 1,2.
    STAGE_X(0, 0);
    STAGE_X(1, 32);
    STAGE_X(2, 64);
#pragma unroll
    for (int n = 0; n < 2; ++n) {
        wKf[0][n] = *(const half8*)(bK + n * 512);
        wQf[0][n] = *(const half8*)(bQ + n * 512);
    }
    asm volatile("s_waitcnt vmcnt(8)" ::: "memory");
    __builtin_amdgcn_s_barrier();

#pragma unroll
    for (int kt = 0; kt < NT3; ++kt) {
        const int cur = kt & 3, par = kt & 1, nx = par ^ 1;
        // issue W(kt+1) frag loads first (their reg-dep wait next iter also
        // retires this iter's older X stage -> counted vmcnt, never 0)
        if (kt < NT3 - 1) {
#pragma unroll
            for (int n = 0; n < 2; ++n) {
                wKf[nx][n] = *(const half8*)(bK + ((size_t)(kt + 1) * 4 + n) * 512);
                wQf[nx][n] = *(const half8*)(bQ + ((size_t)(kt + 1) * 4 + n) * 512);
            }
        }
        if (kt < NT3 - 3) STAGE_X((kt + 3) & 3, (kt + 3) * 32);

        half8 aF[4];
#pragma unroll
        for (int m = 0; m < 4; ++m) aF[m] = *(const half8*)(Xs[cur] + offA[m]);
#pragma unroll
        for (int n = 0; n < 2; ++n)
#pragma unroll
            for (int m = 0; m < 4; ++m) {
                accK[m][n] = __builtin_amdgcn_mfma_f32_16x16x32_f16(aF[m], wKf[par][n], accK[m][n], 0, 0, 0);
                accQ[m][n] = __builtin_amdgcn_mfma_f32_16x16x32_f16(aF[m], wQf[par][n], accQ[m][n], 0, 0, 0);
            }
        if (kt < NT3 - 1) __builtin_amdgcn_s_barrier();
    }
#undef STAGE_X

    // epilogue: tanh, product, reduce over f, combine 2 f-wave-cols
#pragma unroll
    for (int m = 0; m < 4; ++m) {
        float s[4] = {0.f, 0.f, 0.f, 0.f};
#pragma unroll
        for (int n = 0; n < 2; ++n)
#pragma unroll
            for (int j = 0; j < 4; ++j)
                s[j] += tanhf(accQ[m][n][j]) * tanhf(accK[m][n][j]);
#pragma unroll
        for (int j = 0; j < 4; ++j) {
            s[j] += __shfl_xor(s[j], 1);
            s[j] += __shfl_xor(s[j], 2);
            s[j] += __shfl_xor(s[j], 4);
            s[j] += __shfl_xor(s[j], 8);
        }
        if ((lane & 15) == 0) {
            int g = lane >> 4;
#pragma unroll
            for (int j = 0; j < 4; ++j)
                sred[w & 1][wr + m * 16 + g * 4 + j] = s[j];
        }
    }
    __syncthreads();
    if (t < TB3)
        part[(size_t)fb * TOK + tok0 + t] = sred[0][t] + sred[1][t];
}

// ------------- kernel 2: per-batch softmax over S -------------
__global__ void softmax_k(const float* __restrict__ part, float* __restrict__ out) {
    __shared__ float sc[S_];
    __shared__ float red[256];
    const int b = blockIdx.x, t = threadIdx.x;
    float lmax = -1e30f;
    for (int i = t; i < S_; i += 256) {
        float s = 0.f;
#pragma unroll
        for (int fb = 0; fb < NFB3; ++fb) s += part[(size_t)fb * TOK + b * S_ + i];
        sc[i] = s;
        lmax = fmaxf(lmax, s);
    }
    red[t] = lmax; __syncthreads();
    for (int o = 128; o > 0; o >>= 1) { if (t < o) red[t] = fmaxf(red[t], red[t + o]); __syncthreads(); }
    const float mx = red[0]; __syncthreads();
    float lsum = 0.f;
    for (int i = t; i < S_; i += 256) { float e = expf(sc[i] - mx); sc[i] = e; lsum += e; }
    red[t] = lsum; __syncthreads();
    for (int o = 128; o > 0; o >>= 1) { if (t < o) red[t] += red[t + o]; __syncthreads(); }
    const float inv = 1.0f / red[0];
    for (int i = t; i < S_; i += 256)
        out[(size_t)B_ * F_ + (size_t)b * S_ + i] = sc[i] * inv;
}

// ------------- kernel 3: sparse value pass, NSV chunks, groups of 8 -------------
__launch_bounds__(256)
__global__ void value_k4(const float* __restrict__ x, const float* __restrict__ Wv,
                         const float* __restrict__ p_in, float* __restrict__ vpart) {
    __shared__ __align__(16) float xs[8][D_];   // 32 KB
    __shared__ float ps[CSV];
    __shared__ int   idxs[CSV];
    __shared__ int   wsum[4];
    __shared__ int   rbase_s;
    const int b = blockIdx.x, c = blockIdx.y;
    const int t = threadIdx.x, lane = t & 63, w = t >> 6;
    const int s0 = c * CSV;

    if (t == 0) rbase_s = 0;
    __syncthreads();
#pragma unroll 1
    for (int r = 0; r < 4; ++r) {
        int i = r * 256 + t;
        float p = p_in[(size_t)b * S_ + s0 + i];
        bool flag = p > 1e-7f;
        unsigned long long mask = __ballot(flag);
        if (lane == 0) wsum[w] = __popcll(mask);
        __syncthreads();
        int base = rbase_s;
#pragma unroll
        for (int k = 0; k < 4; ++k) if (k < w) base += wsum[k];
        if (flag) {
            int pos = base + __popcll(mask & ((1ull << lane) - 1ull));
            idxs[pos] = s0 + i;
            ps[pos] = p;
        }
        __syncthreads();
        if (t == 0) rbase_s += wsum[0] + wsum[1] + wsum[2] + wsum[3];
        __syncthreads();
    }
    const int cnt = rbase_s;

    float4 acc = {0.f, 0.f, 0.f, 0.f};
    for (int g = 0; g < cnt; g += 8) {
        __syncthreads();
#pragma unroll
        for (int r = 0; r < 8; ++r) {
            float4 v = {0.f, 0.f, 0.f, 0.f};
            if (g + r < cnt)
                v = ((const float4*)(x + ((size_t)b * S_ + idxs[g + r]) * D_))[t];
            ((float4*)xs[r])[t] = v;
        }
        __syncthreads();
        float4 a[8] = {};
#pragma unroll 2
        for (int dq = 0; dq < D_ / 4; ++dq) {
            const float* wrp = Wv + (size_t)dq * 4 * F_;
            float4 wv0 = ((const float4*)(wrp        ))[t];
            float4 wv1 = ((const float4*)(wrp + F_   ))[t];
            float4 wv2 = ((const float4*)(wrp + 2*F_ ))[t];
            float4 wv3 = ((const float4*)(wrp + 3*F_ ))[t];
#pragma unroll
            for (int r = 0; r < 8; ++r) {
                float4 xr = ((const float4*)xs[r])[dq];
                fma4(a[r], xr.x, wv0); fma4(a[r], xr.y, wv1);
                fma4(a[r], xr.z, wv2); fma4(a[r], xr.w, wv3);
            }
        }
#pragma unroll
        for (int r = 0; r < 8; ++r)
            if (g + r < cnt) wtanh4(acc, ps[g + r], a[r]);
    }
    ((float4*)(vpart + ((size_t)c * B_ + b) * F_))[t] = acc;
}

// ------------- kernel 4: reduce chunk partials -------------
__global__ void value_red(const float* __restrict__ vpart, float* __restrict__ out) {
    int i = blockIdx.x * 256 + threadIdx.x;
    float s = 0.f;
#pragma unroll
    for (int c = 0; c < NSV; ++c) s += vpart[(size_t)c * B_ * F_ + i];
    out[i] = s;
}

extern "C" void kernel_launch(void* const* d_in, const int* in_sizes, int n_in,
                              void* d_out, int out_size, void* d_ws, size_t ws_size,
                              hipStream_t stream) {
    const float* x  = (const float*)d_in[0];
    const float* Wk = (const float*)d_in[1];
    const float* Wq = (const float*)d_in[2];
    const float* Wv = (const float*)d_in[3];
    float* out = (float*)d_out;
    char* ws = (char*)d_ws;

    f16*   xh   = (f16*)ws;                                              // 128 MB
    f16*   wtf  = (f16*)(ws + (size_t)TOK * D_ * 2);                     // 4 MB frag-major W
    float* part = (float*)(ws + (size_t)TOK * D_ * 2 + 2 * (size_t)D_ * F_ * 2); // 4 MB

    cvt_x<<<TOK * D_ / 8 / 256, 256, 0, stream>>>(x, xh);
    cvt_w2<<<1024, 256, 0, stream>>>(Wk, Wq, wtf);
    score_gemm<<<NFB3 * (TOK / TB3), 256, 0, stream>>>(xh, wtf, part);
    softmax_k<<<B_, 256, 0, stream>>>(part, out);
    float* vpart = part;
    const float* p_in = out + (size_t)B_ * F_;
    value_k4<<<dim3(B_, NSV), 256, 0, stream>>>(x, Wv, p_in, vpart);
    value_red<<<B_ * F_ / 256, 256, 0, stream>>>(vpart, out);
}

// Round 10
// 575.675 us; speedup vs baseline: 1.1027x; 1.0251x over previous
//
#include <hip/hip_runtime.h>
#include <hip/hip_bf16.h>
#include <math.h>
#include <stdint.h>

typedef _Float16 f16;
typedef _Float16 half8 __attribute__((ext_vector_type(8)));
typedef float f32x4 __attribute__((ext_vector_type(4)));

#define B_ 16
#define S_ 4096
#define D_ 1024
#define F_ 1024
#define TOK (B_*S_)
#define TB3 128        // token tile
#define FB3 64         // f tile
#define NFB3 16        // F_/FB3
#define NT3 32         // D_/32 K-tiles
#define NSV 4          // value-pass S chunks
#define CSV (S_/NSV)   // 1024

// async global->LDS, 16B per lane; lds dest = wave-uniform base + lane*16 (HW)
__device__ __forceinline__ void gload_lds16(const void* g, void* l) {
    __builtin_amdgcn_global_load_lds(
        (__attribute__((address_space(1))) const unsigned int*)(unsigned long long)(uintptr_t)g,
        (__attribute__((address_space(3))) unsigned int*)(unsigned int)(uintptr_t)l,
        16, 0, 0);
}

__device__ __forceinline__ void fma4(float4& a, float s, const float4& wv) {
    a.x += s * wv.x; a.y += s * wv.y; a.z += s * wv.z; a.w += s * wv.w;
}
__device__ __forceinline__ void wtanh4(float4& acc, float pw, const float4& a) {
    acc.x += pw * tanhf(a.x); acc.y += pw * tanhf(a.y);
    acc.z += pw * tanhf(a.z); acc.w += pw * tanhf(a.w);
}

// ---------------- kernel 0a: convert x fp32 -> fp16 ----------------
__global__ void cvt_x(const float* __restrict__ x, f16* __restrict__ xh) {
    size_t i = ((size_t)blockIdx.x * 256 + threadIdx.x) * 8;
    float4 a = *(const float4*)(x + i);
    float4 b = *(const float4*)(x + i + 4);
    half8 h = {(f16)a.x,(f16)a.y,(f16)a.z,(f16)a.w,
               (f16)b.x,(f16)b.y,(f16)b.z,(f16)b.w};
    *(half8*)(xh + i) = h;
}

// ------- kernel 0b: pack Wk,Wq (fp32 [D][F]) -> MFMA-fragment-major f16 -------
// frag gw = ((mat*16+fb)*32 + kt)*4 + nblk ; lane l holds f = fb*64+nblk*16+(l&15),
// k = kt*32+(l>>4)*8..+8 (B-operand of mfma_f32_16x16x32_f16), contiguous per wave.
__global__ void cvt_w2(const float* __restrict__ Wk, const float* __restrict__ Wq,
                       f16* __restrict__ wtf) {
    const int gw   = blockIdx.x * 4 + (threadIdx.x >> 6);   // 0..4095
    const int lane = threadIdx.x & 63;
    const int nblk = gw & 3, kt = (gw >> 2) & 31, fb = (gw >> 7) & 15, mat = gw >> 11;
    const float* W = mat ? Wq : Wk;
    const int f  = fb * 64 + nblk * 16 + (lane & 15);
    const int d0 = kt * 32 + (lane >> 4) * 8;
    half8 h;
#pragma unroll
    for (int e = 0; e < 8; ++e) h[e] = (f16)W[(size_t)(d0 + e) * F_ + f];
    *(half8*)(wtf + (size_t)gw * 512 + lane * 8) = h;
}

// ------------- kernel 1: fused Q/K GEMM + tanh + diag-dot partials -------------
// 128x64 tile, 4 waves, each 64 tok x 32 f for BOTH matrices.
// X: LDS-staged (4 slots x 8KB, gload_lds, T2 swizzle both-sides, prefetch-3).
// W: NO LDS — fragment-major global loads (L2-hot), register ping-pong.
// T1 FIXED: XCD chunk of 1024 origs; fb FASTEST within chunk (16 fb share each
// X tile from L2; per-XCD W slice 4MB stays L2-hot; X fetched once chip-wide).
__launch_bounds__(256, 3)
__global__ void score_gemm(const f16* __restrict__ xh, const f16* __restrict__ wtf,
                           float* __restrict__ part) {
    __shared__ __align__(16) f16 Xs[4][TB3 * 32];   // 4 x 8 KB
    __shared__ float sred[2][TB3];                  // 1 KB

    const int hid  = blockIdx.x;
    const int orig = (hid & 7) * 1024 + (hid >> 3);
    const int fb   = orig & 15;                 // FAST: 16 fb per X tile
    const int tok0 = (orig >> 4) * TB3;         // 64 contiguous tok tiles per XCD

    const int t = threadIdx.x, lane = t & 63, w = t >> 6;
    const int wr = (w >> 1) * 64;     // token offset of wave sub-tile
    const int wc = (w & 1) * 32;      // f offset of wave sub-tile

    // X staging sources, pre-swizzled quad (involution q ^ ((row>>1)&3))
    const int rx0 = t >> 2,         qx0 = (t & 3) ^ ((rx0 >> 1) & 3);
    const int rx1 = (t + 256) >> 2, qx1 = (t & 3) ^ ((rx1 >> 1) & 3);
    const f16* srcX0 = xh + (size_t)(tok0 + rx0) * D_ + qx0 * 8;
    const f16* srcX1 = xh + (size_t)(tok0 + rx1) * D_ + qx1 * 8;
    const int wbase = w * 1024;       // wave-uniform LDS byte base

    // A-fragment read offsets (swizzled read side)
    int offA[4];
#pragma unroll
    for (int m = 0; m < 4; ++m) {
        int row = wr + m * 16 + (lane & 15);
        int q   = (lane >> 4) ^ ((row >> 1) & 3);
        offA[m] = row * 32 + q * 8;
    }

    // W fragment base pointers (per-lane): frag elem off = ((fb*32+kt)*4+nblk)*512
    const f16* bK = wtf + (((size_t)fb * NT3 * 4) + 2 * (w & 1)) * 512 + lane * 8;
    const f16* bQ = bK + (size_t)NFB3 * NT3 * 4 * 512;   // mat=1 half

#define STAGE_X(sl, kof) do {                                         \
        gload_lds16(srcX0 + (kof), (char*)Xs[sl] + wbase);            \
        gload_lds16(srcX1 + (kof), (char*)Xs[sl] + 4096 + wbase);     \
    } while (0)

    f32x4 accK[4][2] = {};
    f32x4 accQ[4][2] = {};
    half8 wKf[2][2], wQf[2][2];

    // prologue: X0,X1,X2 staged, then W(0) frags; vmcnt(8) forces X0;
    // MFMA(0)'s auto-wait on W(0) (newest) drains X1,X2 for iters 1,2.
    STAGE_X(0, 0);
    STAGE_X(1, 32);
    STAGE_X(2, 64);
#pragma unroll
    for (int n = 0; n < 2; ++n) {
        wKf[0][n] = *(const half8*)(bK + n * 512);
        wQf[0][n] = *(const half8*)(bQ + n * 512);
    }
    asm volatile("s_waitcnt vmcnt(8)" ::: "memory");
    __builtin_amdgcn_s_barrier();

#pragma unroll
    for (int kt = 0; kt < NT3; ++kt) {
        const int cur = kt & 3, par = kt & 1, nx = par ^ 1;
        if (kt < NT3 - 1) {
#pragma unroll
            for (int n = 0; n < 2; ++n) {
                wKf[nx][n] = *(const half8*)(bK + ((size_t)(kt + 1) * 4 + n) * 512);
                wQf[nx][n] = *(const half8*)(bQ + ((size_t)(kt + 1) * 4 + n) * 512);
            }
        }
        if (kt < NT3 - 3) STAGE_X((kt + 3) & 3, (kt + 3) * 32);

        half8 aF[4];
#pragma unroll
        for (int m = 0; m < 4; ++m) aF[m] = *(const half8*)(Xs[cur] + offA[m]);
#pragma unroll
        for (int n = 0; n < 2; ++n)
#pragma unroll
            for (int m = 0; m < 4; ++m) {
                accK[m][n] = __builtin_amdgcn_mfma_f32_16x16x32_f16(aF[m], wKf[par][n], accK[m][n], 0, 0, 0);
                accQ[m][n] = __builtin_amdgcn_mfma_f32_16x16x32_f16(aF[m], wQf[par][n], accQ[m][n], 0, 0, 0);
            }
        if (kt < NT3 - 1) __builtin_amdgcn_s_barrier();
    }
#undef STAGE_X

    // epilogue: tanh, product, reduce over f, combine 2 f-wave-cols
#pragma unroll
    for (int m = 0; m < 4; ++m) {
        float s[4] = {0.f, 0.f, 0.f, 0.f};
#pragma unroll
        for (int n = 0; n < 2; ++n)
#pragma unroll
            for (int j = 0; j < 4; ++j)
                s[j] += tanhf(accQ[m][n][j]) * tanhf(accK[m][n][j]);
#pragma unroll
        for (int j = 0; j < 4; ++j) {
            s[j] += __shfl_xor(s[j], 1);
            s[j] += __shfl_xor(s[j], 2);
            s[j] += __shfl_xor(s[j], 4);
            s[j] += __shfl_xor(s[j], 8);
        }
        if ((lane & 15) == 0) {
            int g = lane >> 4;
#pragma unroll
            for (int j = 0; j < 4; ++j)
                sred[w & 1][wr + m * 16 + g * 4 + j] = s[j];
        }
    }
    __syncthreads();
    if (t < TB3)
        part[(size_t)fb * TOK + tok0 + t] = sred[0][t] + sred[1][t];
}

// ------------- kernel 2a: reduce fb partials -> scores[tok] -------------
__global__ void sum_k(const float* __restrict__ part, float* __restrict__ scores) {
    int i = blockIdx.x * 256 + threadIdx.x;
    float s = 0.f;
#pragma unroll
    for (int fb = 0; fb < NFB3; ++fb) s += part[(size_t)fb * TOK + i];
    scores[i] = s;
}

// ------------- kernel 2b: per-batch softmax over S -------------
__global__ void softmax_k(const float* __restrict__ scores, float* __restrict__ out) {
    __shared__ float sc[S_];
    __shared__ float red[256];
    const int b = blockIdx.x, t = threadIdx.x;
    float lmax = -1e30f;
    for (int i = t; i < S_; i += 256) {
        float s = scores[(size_t)b * S_ + i];
        sc[i] = s;
        lmax = fmaxf(lmax, s);
    }
    red[t] = lmax; __syncthreads();
    for (int o = 128; o > 0; o >>= 1) { if (t < o) red[t] = fmaxf(red[t], red[t + o]); __syncthreads(); }
    const float mx = red[0]; __syncthreads();
    float lsum = 0.f;
    for (int i = t; i < S_; i += 256) { float e = expf(sc[i] - mx); sc[i] = e; lsum += e; }
    red[t] = lsum; __syncthreads();
    for (int o = 128; o > 0; o >>= 1) { if (t < o) red[t] += red[t + o]; __syncthreads(); }
    const float inv = 1.0f / red[0];
    for (int i = t; i < S_; i += 256)
        out[(size_t)B_ * F_ + (size_t)b * S_ + i] = sc[i] * inv;
}

// ------------- kernel 3: sparse value pass, NSV chunks, groups of 8 -------------
__launch_bounds__(256)
__global__ void value_k4(const float* __restrict__ x, const float* __restrict__ Wv,
                         const float* __restrict__ p_in, float* __restrict__ vpart) {
    __shared__ __align__(16) float xs[8][D_];   // 32 KB
    __shared__ float ps[CSV];
    __shared__ int   idxs[CSV];
    __shared__ int   wsum[4];
    __shared__ int   rbase_s;
    const int b = blockIdx.x, c = blockIdx.y;
    const int t = threadIdx.x, lane = t & 63, w = t >> 6;
    const int s0 = c * CSV;

    if (t == 0) rbase_s = 0;
    __syncthreads();
#pragma unroll 1
    for (int r = 0; r < 4; ++r) {
        int i = r * 256 + t;
        float p = p_in[(size_t)b * S_ + s0 + i];
        bool flag = p > 1e-7f;
        unsigned long long mask = __ballot(flag);
        if (lane == 0) wsum[w] = __popcll(mask);
        __syncthreads();
        int base = rbase_s;
#pragma unroll
        for (int k = 0; k < 4; ++k) if (k < w) base += wsum[k];
        if (flag) {
            int pos = base + __popcll(mask & ((1ull << lane) - 1ull));
            idxs[pos] = s0 + i;
            ps[pos] = p;
        }
        __syncthreads();
        if (t == 0) rbase_s += wsum[0] + wsum[1] + wsum[2] + wsum[3];
        __syncthreads();
    }
    const int cnt = rbase_s;

    float4 acc = {0.f, 0.f, 0.f, 0.f};
    for (int g = 0; g < cnt; g += 8) {
        __syncthreads();
#pragma unroll
        for (int r = 0; r < 8; ++r) {
            float4 v = {0.f, 0.f, 0.f, 0.f};
            if (g + r < cnt)
                v = ((const float4*)(x + ((size_t)b * S_ + idxs[g + r]) * D_))[t];
            ((float4*)xs[r])[t] = v;
        }
        __syncthreads();
        float4 a[8] = {};
#pragma unroll 2
        for (int dq = 0; dq < D_ / 4; ++dq) {
            const float* wrp = Wv + (size_t)dq * 4 * F_;
            float4 wv0 = ((const float4*)(wrp        ))[t];
            float4 wv1 = ((const float4*)(wrp + F_   ))[t];
            float4 wv2 = ((const float4*)(wrp + 2*F_ ))[t];
            float4 wv3 = ((const float4*)(wrp + 3*F_ ))[t];
#pragma unroll
            for (int r = 0; r < 8; ++r) {
                float4 xr = ((const float4*)xs[r])[dq];
                fma4(a[r], xr.x, wv0); fma4(a[r], xr.y, wv1);
                fma4(a[r], xr.z, wv2); fma4(a[r], xr.w, wv3);
            }
        }
#pragma unroll
        for (int r = 0; r < 8; ++r)
            if (g + r < cnt) wtanh4(acc, ps[g + r], a[r]);
    }
    ((float4*)(vpart + ((size_t)c * B_ + b) * F_))[t] = acc;
}

// ------------- kernel 4: reduce chunk partials -------------
__global__ void value_red(const float* __restrict__ vpart, float* __restrict__ out) {
    int i = blockIdx.x * 256 + threadIdx.x;
    float s = 0.f;
#pragma unroll
    for (int c = 0; c < NSV; ++c) s += vpart[(size_t)c * B_ * F_ + i];
    out[i] = s;
}

extern "C" void kernel_launch(void* const* d_in, const int* in_sizes, int n_in,
                              void* d_out, int out_size, void* d_ws, size_t ws_size,
                              hipStream_t stream) {
    const float* x  = (const float*)d_in[0];
    const float* Wk = (const float*)d_in[1];
    const float* Wq = (const float*)d_in[2];
    const float* Wv = (const float*)d_in[3];
    float* out = (float*)d_out;
    char* ws = (char*)d_ws;

    f16*   xh     = (f16*)ws;                                            // 128 MB
    f16*   wtf    = (f16*)(ws + (size_t)TOK * D_ * 2);                   // 4 MB frag-major W
    float* part   = (float*)(ws + (size_t)TOK * D_ * 2 + 2 * (size_t)D_ * F_ * 2); // 4 MB
    float* scores = part + (size_t)NFB3 * TOK;                           // 256 KB

    cvt_x<<<TOK * D_ / 8 / 256, 256, 0, stream>>>(x, xh);
    cvt_w2<<<1024, 256, 0, stream>>>(Wk, Wq, wtf);
    score_gemm<<<NFB3 * (TOK / TB3), 256, 0, stream>>>(xh, wtf, part);
    sum_k<<<TOK / 256, 256, 0, stream>>>(part, scores);
    softmax_k<<<B_, 256, 0, stream>>>(scores, out);
    float* vpart = part;
    const float* p_in = out + (size_t)B_ * F_;
    value_k4<<<dim3(B_, NSV), 256, 0, stream>>>(x, Wv, p_in, vpart);
    value_red<<<B_ * F_ / 256, 256, 0, stream>>>(vpart, out);
}